// Round 1
// baseline (407.102 us; speedup 1.0000x reference)
//
#include <hip/hip_runtime.h>
#include <hip/hip_bf16.h>
#include <math.h>

typedef __attribute__((ext_vector_type(8))) short short8v;   // 8 bf16 (4 VGPR)
typedef __attribute__((ext_vector_type(4))) float float4v;   // 4 f32 acc

#define VMCNT(n) asm volatile("s_waitcnt vmcnt(" #n ")" ::: "memory")
#define LGK0     asm volatile("s_waitcnt lgkmcnt(0)" ::: "memory")

namespace {
constexpr int kBSZ = 16;
constexpr int kNW  = 1024;
constexpr int kT   = 3072;
constexpr int kBED = 128;
constexpr int kWED = 512;
constexpr int kR   = kBSZ * kT;    // 49152
constexpr int kMP  = kBSZ * kNW;   // 16384
}

// bf16 <-> f32 (RNE)
__device__ __forceinline__ unsigned short f2b(float x) {
  unsigned int u = __float_as_uint(x);
  u = u + 0x7FFFu + ((u >> 16) & 1u);
  return (unsigned short)(u >> 16);
}
__device__ __forceinline__ float b2f(unsigned short u) {
  return __uint_as_float(((unsigned int)u) << 16);
}

__device__ __forceinline__ void async16(void* l, const void* g) {
  __builtin_amdgcn_global_load_lds(
      (const __attribute__((address_space(1))) void*)g,
      (__attribute__((address_space(3))) void*)l, 16, 0, 0);
}

// ---------------------------------------------------------------------------
// Embedding -> bf16 (kR, 128)
// ---------------------------------------------------------------------------
__global__ __launch_bounds__(256) void k_embed(
    const int* __restrict__ tok, const int* __restrict__ msk,
    const float* __restrict__ emb, unsigned short* __restrict__ out) {
  int idx = blockIdx.x * 256 + threadIdx.x;   // kR * 32
  int row = idx >> 5, c4 = idx & 31;
  const float4* e4 = (const float4*)emb;
  float4 a = e4[tok[row] * 32 + c4];
  float4 b = e4[(msk[row] ? 4 : 0) * 32 + c4];
  ushort4 o;
  o.x = f2b(a.x + b.x); o.y = f2b(a.y + b.y);
  o.z = f2b(a.z + b.z); o.w = f2b(a.w + b.w);
  ((ushort4*)out)[idx] = o;
}

// ---------------------------------------------------------------------------
// Weight prep: conv W (3,CIN,512) f32 -> (3,512,CIN) bf16 ; plain f32->bf16
// ---------------------------------------------------------------------------
__global__ __launch_bounds__(256) void k_wt_conv(
    const float* __restrict__ W, unsigned short* __restrict__ o, int CIN) {
  int idx = blockIdx.x * 256 + threadIdx.x;
  if (idx >= 3 * kWED * CIN) return;
  int k = idx % CIN, n = (idx / CIN) % kWED, dt = idx / (kWED * CIN);
  o[idx] = f2b(W[(long)(dt * CIN + k) * kWED + n]);
}
__global__ __launch_bounds__(256) void k_f2bk(
    const float* __restrict__ in, unsigned short* __restrict__ o, int n) {
  int idx = blockIdx.x * 256 + threadIdx.x;
  if (idx < n) o[idx] = f2b(in[idx]);
}

// ---------------------------------------------------------------------------
// Per-batch inclusive cumsum of pool_lengths (hoisted: GEMMs early-exit on it)
// ---------------------------------------------------------------------------
__global__ void k_cumsum(const int* __restrict__ pl, int* __restrict__ cum) {
  __shared__ int s[kNW];
  int b = blockIdx.x, i = threadIdx.x;
  s[i] = pl[b * kNW + i];
  __syncthreads();
  for (int off = 1; off < kNW; off <<= 1) {
    int cur = s[i];
    int add = (i >= off) ? s[i - off] : 0;
    __syncthreads();
    s[i] = cur + add;
    __syncthreads();
  }
  cum[b * kNW + i] = s[i];
}

// ---------------------------------------------------------------------------
// Conv1d as GEMM with +-1 halo rows (unchanged this round).
// ---------------------------------------------------------------------------
template <int CIN, bool RESID>
__global__ __launch_bounds__(256, 2) void k_convm(
    const unsigned short* __restrict__ X,
    const unsigned short* __restrict__ Wt,
    const float* __restrict__ bias,
    const unsigned short* __restrict__ resid,
    const int* __restrict__ cum,
    unsigned short* __restrict__ out) {
  const int row0 = blockIdx.x * 128, n0 = blockIdx.y * 128;
  const int b = row0 / kT;
  const int t0 = row0 % kT;
  if (t0 >= cum[b * kNW + kNW - 1] + 2) return;   // early exit: dead rows

  __shared__ short lds[(130 + 384) * 64];
  short* As = lds;              // [130][64] rows = global t0-1 .. t0+128
  short* Bs = lds + 130 * 64;   // [3*128][64]
  const int tid = threadIdx.x, wave = tid >> 6, lane = tid & 63;
  const int q = lane >> 4, rr = lane & 15;
  const int jhi = lane >> 3, jlo = lane & 7;
  const bool lo_ok = (t0 > 0), hi_ok = (t0 + 128 < kT);
  const int wr = (wave >> 1) * 64, wc = (wave & 1) * 64;

  float4v acc[4][4] = {};

  for (int k0 = 0; k0 < CIN; k0 += 64) {
#pragma unroll
    for (int i = 0; i < 4; ++i) {
      int o = wave + 4 * i;
      int m = 1 + o * 8 + jhi;
      int c16 = jlo ^ (m & 7);
      async16((char*)As + (1 + o * 8) * 128,
              X + ((long)(row0 + m - 1) * CIN + k0 + c16 * 8));
    }
    if (tid < 16) {
      int m = (tid < 8) ? 0 : 129;
      int u = tid & 7;
      int c16 = u ^ (m & 7);
      bool ok = (tid < 8) ? lo_ok : hi_ok;
      short8v v = {0, 0, 0, 0, 0, 0, 0, 0};
      if (ok) v = *(const short8v*)(X + ((long)(row0 + m - 1) * CIN + k0 + c16 * 8));
      *(short8v*)((char*)As + m * 128 + u * 16) = v;
    }
#pragma unroll
    for (int i = 0; i < 12; ++i) {
      int o = wave + 4 * i;
      int br = o * 8 + jhi;
      int c16 = jlo ^ (br & 7);
      int dt = br >> 7, n = br & 127;
      async16((char*)Bs + o * 8 * 128,
              Wt + ((long)(dt * kWED + n0 + n) * CIN + k0 + c16 * 8));
    }
    __syncthreads();
#pragma unroll
    for (int dt = 0; dt < 3; ++dt) {
      const int abase = wr + rr + dt;
      const int asw = abase & 7;
      const int bbase = wc + rr;
      const int bsw = rr & 7;
#pragma unroll
      for (int kk = 0; kk < 2; ++kk) {
        short8v a[4], b[4];
#pragma unroll
        for (int mf = 0; mf < 4; ++mf)
          a[mf] = *(const short8v*)((char*)As + (abase + mf * 16) * 128 +
                                    (((kk * 4 + q) ^ asw) * 16));
#pragma unroll
        for (int nf = 0; nf < 4; ++nf)
          b[nf] = *(const short8v*)((char*)Bs + (dt * 128 + bbase + nf * 16) * 128 +
                                    (((kk * 4 + q) ^ bsw) * 16));
#pragma unroll
        for (int mf = 0; mf < 4; ++mf)
#pragma unroll
          for (int nf = 0; nf < 4; ++nf)
            acc[mf][nf] = __builtin_amdgcn_mfma_f32_16x16x32_bf16(
                a[mf], b[nf], acc[mf][nf], 0, 0, 0);
      }
    }
    __syncthreads();
  }
#pragma unroll
  for (int nf = 0; nf < 4; ++nf) {
    int col = n0 + wc + nf * 16 + rr;
    float bv = bias[col];
#pragma unroll
    for (int mf = 0; mf < 4; ++mf)
#pragma unroll
      for (int r = 0; r < 4; ++r) {
        long row = row0 + wr + mf * 16 + q * 4 + r;
        float y = fmaxf(acc[mf][nf][r] + bv, 0.f);
        if (RESID) y += b2f(resid[row * kWED + col]);
        out[row * kWED + col] = f2b(y);
      }
  }
}

// ---------------------------------------------------------------------------
// Highway layer — 8-phase counted-vmcnt rewrite (T3+T4+T5 on top of T2).
// Tile 256 rows x 128 cols, 512 thr = 8 waves (2M x 4N, per-wave 128x32,
// h+g fused). LDS 128 KiB = 2 dbuf x 2 kk x (A 256x32 | B 256x32) bf16.
// Per K-tile (BK=64): 4 phases = quadrant (kk, h|g), 16 MFMA each; one
// 16 KB part (2 global_load_lds instr/wave) staged per phase into the idle
// buffer; counted vmcnt only (never 0 in loop).
//
// Part schedule (per-wave instr counts; stage order A-k0,B-k0,A-k1,B-k1 of
// tile kt+1 at phases 0..3 of tile kt):
//   end ph0: VMCNT(6) -> forces B-k0(kt) landed   (needed ph1)
//   end ph1: VMCNT(4) -> forces A-k1(kt) landed   (needed ph2)
//   end ph2: VMCNT(6) -> forces B-k1(kt) landed   (needed ph3)
//   end ph3: VMCNT(4) -> forces A-k0,B-k0(kt+1)   (needed next ph0)
// Buffer being staged (nb) was fully consumed by tile kt-1 before tile kt
// began (its reads drained by that tile's LGK0+barrier) -> no LDS race.
// ---------------------------------------------------------------------------
__global__ __launch_bounds__(512, 2) void k_hw8(
    const unsigned short* __restrict__ X,
    const unsigned short* __restrict__ Wb,
    const float* __restrict__ bias,
    const int* __restrict__ cum,
    unsigned short* __restrict__ out) {
  const int row0 = blockIdx.x * 256, n0 = blockIdx.y * 128;
  const int bb = row0 / kT, t0 = row0 % kT;
  if (t0 >= cum[bb * kNW + kNW - 1] + 2) return;   // early exit: dead rows

  __shared__ alignas(128) char ldsb[131072];   // [buf][kk][A 16K | B 16K]

  const int tid = threadIdx.x;
  const int wv = tid >> 6, lane = tid & 63;
  const int ql = lane >> 4, rr = lane & 15;
  const int wr = (wv >> 2) * 128;        // M half (rows)
  const int wc = (wv & 3) * 32;          // N quarter (cols)
  const int sdr = lane >> 2, sl = lane & 3;   // staging: row-in-chunk, slot

  float4v acch[8][2] = {}, accg[8][2] = {};
  short8v a[8], bh[2], bg[2];

  // stage one 16KB part: 2 loads (lh) x 512 thr x 16B. LDS dest linear,
  // source pre-swizzled: dest slot s holds global chunk s ^ ((row>>1)&3).
  auto stA = [&](int bf, int kt, int kk) {
#pragma unroll
    for (int lh = 0; lh < 2; ++lh) {
      int dr = lh * 128 + wv * 16 + sdr;
      int ch = sl ^ ((dr >> 1) & 3);
      async16(ldsb + bf * 65536 + kk * 32768 + lh * 8192 + wv * 1024,
              X + (long)(row0 + dr) * kWED + kt * 64 + kk * 32 + ch * 8);
    }
  };
  auto stB = [&](int bf, int kt, int kk) {
#pragma unroll
    for (int lh = 0; lh < 2; ++lh) {
      int dr = lh * 128 + wv * 16 + sdr;
      int ch = sl ^ ((dr >> 1) & 3);
      int wrow = n0 + dr + (lh ? 384 : 0);   // rows 0-127: h, 128-255: g(+512)
      async16(ldsb + bf * 65536 + kk * 32768 + 16384 + lh * 8192 + wv * 1024,
              Wb + (long)wrow * kWED + kt * 64 + kk * 32 + ch * 8);
    }
  };
  auto ldA = [&](int bf, int kk, int row) {
    return *(const short8v*)(ldsb + bf * 65536 + kk * 32768 + row * 64 +
                             ((ql ^ ((row >> 1) & 3)) * 16));
  };
  auto ldB = [&](int bf, int kk, int row) {
    return *(const short8v*)(ldsb + bf * 65536 + kk * 32768 + 16384 + row * 64 +
                             ((ql ^ ((row >> 1) & 3)) * 16));
  };

  // prologue: tile 0, all 4 parts; p0,p1 must land (p2,p3 may stay in flight)
  stA(0, 0, 0); stB(0, 0, 0); stA(0, 0, 1); stB(0, 0, 1);
  VMCNT(4);
  __builtin_amdgcn_s_barrier();

  for (int kt = 0; kt < 8; ++kt) {
    const int bf = kt & 1, nb = bf ^ 1;
    const bool pf = kt < 7;

    // ---- phase 0: (kk=0, h) ----
#pragma unroll
    for (int mf = 0; mf < 8; ++mf) a[mf] = ldA(bf, 0, wr + rr + mf * 16);
#pragma unroll
    for (int nf = 0; nf < 2; ++nf) bh[nf] = ldB(bf, 0, wc + rr + nf * 16);
    if (pf) stA(nb, kt + 1, 0);
    __builtin_amdgcn_s_barrier();
    LGK0; __builtin_amdgcn_sched_barrier(0);
    __builtin_amdgcn_s_setprio(1);
#pragma unroll
    for (int mf = 0; mf < 8; ++mf)
#pragma unroll
      for (int nf = 0; nf < 2; ++nf)
        acch[mf][nf] = __builtin_amdgcn_mfma_f32_16x16x32_bf16(
            a[mf], bh[nf], acch[mf][nf], 0, 0, 0);
    __builtin_amdgcn_s_setprio(0);
    VMCNT(6);
    __builtin_amdgcn_s_barrier();

    // ---- phase 1: (kk=0, g) ----
#pragma unroll
    for (int nf = 0; nf < 2; ++nf) bg[nf] = ldB(bf, 0, 128 + wc + rr + nf * 16);
    if (pf) stB(nb, kt + 1, 0);
    __builtin_amdgcn_s_barrier();
    LGK0; __builtin_amdgcn_sched_barrier(0);
    __builtin_amdgcn_s_setprio(1);
#pragma unroll
    for (int mf = 0; mf < 8; ++mf)
#pragma unroll
      for (int nf = 0; nf < 2; ++nf)
        accg[mf][nf] = __builtin_amdgcn_mfma_f32_16x16x32_bf16(
            a[mf], bg[nf], accg[mf][nf], 0, 0, 0);
    __builtin_amdgcn_s_setprio(0);
    VMCNT(4);
    __builtin_amdgcn_s_barrier();

    // ---- phase 2: (kk=1, h) ----
#pragma unroll
    for (int mf = 0; mf < 8; ++mf) a[mf] = ldA(bf, 1, wr + rr + mf * 16);
#pragma unroll
    for (int nf = 0; nf < 2; ++nf) bh[nf] = ldB(bf, 1, wc + rr + nf * 16);
    if (pf) stA(nb, kt + 1, 1);
    __builtin_amdgcn_s_barrier();
    LGK0; __builtin_amdgcn_sched_barrier(0);
    __builtin_amdgcn_s_setprio(1);
#pragma unroll
    for (int mf = 0; mf < 8; ++mf)
#pragma unroll
      for (int nf = 0; nf < 2; ++nf)
        acch[mf][nf] = __builtin_amdgcn_mfma_f32_16x16x32_bf16(
            a[mf], bh[nf], acch[mf][nf], 0, 0, 0);
    __builtin_amdgcn_s_setprio(0);
    VMCNT(6);
    __builtin_amdgcn_s_barrier();

    // ---- phase 3: (kk=1, g) ----
#pragma unroll
    for (int nf = 0; nf < 2; ++nf) bg[nf] = ldB(bf, 1, 128 + wc + rr + nf * 16);
    if (pf) stB(nb, kt + 1, 1);
    __builtin_amdgcn_s_barrier();
    LGK0; __builtin_amdgcn_sched_barrier(0);
    __builtin_amdgcn_s_setprio(1);
#pragma unroll
    for (int mf = 0; mf < 8; ++mf)
#pragma unroll
      for (int nf = 0; nf < 2; ++nf)
        accg[mf][nf] = __builtin_amdgcn_mfma_f32_16x16x32_bf16(
            a[mf], bg[nf], accg[mf][nf], 0, 0, 0);
    __builtin_amdgcn_s_setprio(0);
    VMCNT(4);
    __builtin_amdgcn_s_barrier();
  }

  // epilogue: h/g combine + residual pass-through
#pragma unroll
  for (int nf = 0; nf < 2; ++nf) {
    int col = n0 + wc + nf * 16 + rr;
    float bhv = bias[col], bgv = bias[512 + col];
#pragma unroll
    for (int mf = 0; mf < 8; ++mf)
#pragma unroll
      for (int r = 0; r < 4; ++r) {
        long row = row0 + wr + mf * 16 + ql * 4 + r;
        float h = fmaxf(acch[mf][nf][r] + bhv, 0.f);
        float g = 1.f / (1.f + __expf(-(accg[mf][nf][r] + bgv)));
        float xv = b2f(X[row * kWED + col]);
        out[row * kWED + col] = f2b(g * h + (1.f - g) * xv);
      }
  }
}

// ---------------------------------------------------------------------------
// Projection: pooled (kMP,512) bf16 @ pW.T + pb -> f32 out (unchanged)
// ---------------------------------------------------------------------------
__global__ __launch_bounds__(256, 2) void k_proj(
    const unsigned short* __restrict__ A,
    const unsigned short* __restrict__ Wb,   // (512,512) [n][k] bf16
    const float* __restrict__ bias,
    float* __restrict__ out) {
  __shared__ short lds[(128 + 128) * 64];
  short* As = lds;
  short* Bs = lds + 128 * 64;
  const int tid = threadIdx.x, wave = tid >> 6, lane = tid & 63;
  const int q = lane >> 4, rr = lane & 15;
  const int jhi = lane >> 3, jlo = lane & 7;
  const int row0 = blockIdx.x * 128, n0 = blockIdx.y * 128;
  const int wr = (wave >> 1) * 64, wc = (wave & 1) * 64;

  float4v acc[4][4] = {};

  for (int k0 = 0; k0 < kWED; k0 += 64) {
#pragma unroll
    for (int i = 0; i < 4; ++i) {
      int o = wave + 4 * i;
      int m = o * 8 + jhi;
      int c16 = jlo ^ (m & 7);
      async16((char*)As + o * 8 * 128,
              A + ((long)(row0 + m) * kWED + k0 + c16 * 8));
    }
#pragma unroll
    for (int i = 0; i < 4; ++i) {
      int o = wave + 4 * i;
      int n = o * 8 + jhi;
      int c16 = jlo ^ (n & 7);
      async16((char*)Bs + o * 8 * 128,
              Wb + ((long)(n0 + n) * kWED + k0 + c16 * 8));
    }
    __syncthreads();
    const int abase = wr + rr, bbase = wc + rr;
    const int sw = rr & 7;
#pragma unroll
    for (int kk = 0; kk < 2; ++kk) {
      short8v a[4], b[4];
#pragma unroll
      for (int mf = 0; mf < 4; ++mf)
        a[mf] = *(const short8v*)((char*)As + (abase + mf * 16) * 128 +
                                  (((kk * 4 + q) ^ sw) * 16));
#pragma unroll
      for (int nf = 0; nf < 4; ++nf)
        b[nf] = *(const short8v*)((char*)Bs + (bbase + nf * 16) * 128 +
                                  (((kk * 4 + q) ^ sw) * 16));
#pragma unroll
      for (int mf = 0; mf < 4; ++mf)
#pragma unroll
        for (int nf = 0; nf < 4; ++nf)
          acc[mf][nf] = __builtin_amdgcn_mfma_f32_16x16x32_bf16(
              a[mf], b[nf], acc[mf][nf], 0, 0, 0);
    }
    __syncthreads();
  }
#pragma unroll
  for (int nf = 0; nf < 4; ++nf) {
    int col = n0 + wc + nf * 16 + rr;
    float bv = bias[col];
#pragma unroll
    for (int mf = 0; mf < 4; ++mf)
#pragma unroll
      for (int r = 0; r < 4; ++r) {
        long row = row0 + wr + mf * 16 + q * 4 + r;
        out[row * kWED + col] = acc[mf][nf][r] + bv;
      }
  }
}

// ---------------------------------------------------------------------------
__global__ __launch_bounds__(128) void k_pool(
    const unsigned short* __restrict__ x, const int* __restrict__ cum,
    unsigned short* __restrict__ pooled) {
  int bw = blockIdx.x;
  int b = bw >> 10, w = bw & 1023;
  int s = (w == 0) ? 0 : cum[bw - 1];
  int e = cum[bw];
  int c = threadIdx.x;
  float m0 = -INFINITY, m1 = -INFINITY, m2 = -INFINITY, m3 = -INFINITY;
  for (int t = s; t < e; ++t) {
    ushort4 v = ((const ushort4*)(x + (long)(b * kT + t) * kWED))[c];
    m0 = fmaxf(m0, b2f(v.x)); m1 = fmaxf(m1, b2f(v.y));
    m2 = fmaxf(m2, b2f(v.z)); m3 = fmaxf(m3, b2f(v.w));
  }
  if (e <= s) { m0 = m1 = m2 = m3 = 0.f; }
  ushort4 o;
  o.x = f2b(m0); o.y = f2b(m1); o.z = f2b(m2); o.w = f2b(m3);
  ((ushort4*)(pooled + (long)bw * kWED))[c] = o;
}

// ---------------------------------------------------------------------------
extern "C" void kernel_launch(void* const* d_in, const int* in_sizes, int n_in,
                              void* d_out, int out_size, void* d_ws, size_t ws_size,
                              hipStream_t stream) {
  (void)in_sizes; (void)n_in; (void)out_size; (void)ws_size;

  const int*   tok = (const int*)d_in[0];
  const int*   msk = (const int*)d_in[1];
  const int*   pl  = (const int*)d_in[2];
  const float* emb = (const float*)d_in[3];
  const float* c0W = (const float*)d_in[4];
  const float* c0b = (const float*)d_in[5];
  const float* c1W = (const float*)d_in[6];
  const float* c1b = (const float*)d_in[7];
  const float* h0W = (const float*)d_in[8];
  const float* h0b = (const float*)d_in[9];
  const float* h1W = (const float*)d_in[10];
  const float* h1b = (const float*)d_in[11];
  const float* pW  = (const float*)d_in[12];
  const float* pb  = (const float*)d_in[13];

  unsigned short* xb0 = (unsigned short*)d_ws;              // (kR,512) bf16
  unsigned short* xb1 = xb0 + (size_t)kR * kWED;            // (kR,512) bf16
  unsigned short* cw0 = xb1 + (size_t)kR * kWED;            // (3,512,128)
  unsigned short* cw1 = cw0 + 3 * kWED * kBED;              // (3,512,512)
  unsigned short* hw0 = cw1 + 3 * kWED * kWED;              // (2,1024,512)
  unsigned short* hw1 = hw0 + 2 * 1024 * kWED;
  unsigned short* pwb = hw1 + 2 * 1024 * kWED;              // (512,512)
  int* cum = (int*)(pwb + kWED * kWED);

  // cumsum first: GEMMs early-exit on src lengths
  k_cumsum<<<kBSZ, kNW, 0, stream>>>(pl, cum);

  k_wt_conv<<<(3 * kWED * kBED + 255) / 256, 256, 0, stream>>>(c0W, cw0, kBED);
  k_wt_conv<<<(3 * kWED * kWED + 255) / 256, 256, 0, stream>>>(c1W, cw1, kWED);
  k_f2bk<<<(2 * 1024 * kWED + 255) / 256, 256, 0, stream>>>(h0W, hw0, 2 * 1024 * kWED);
  k_f2bk<<<(2 * 1024 * kWED + 255) / 256, 256, 0, stream>>>(h1W, hw1, 2 * 1024 * kWED);
  k_f2bk<<<(kWED * kWED + 255) / 256, 256, 0, stream>>>(pW, pwb, kWED * kWED);

  k_embed<<<kR * 32 / 256, 256, 0, stream>>>(tok, msk, emb, xb0);

  dim3 g1(kR / 128, kWED / 128);   // (384, 4) — conv kernels
  dim3 gh(kR / 256, kWED / 128);   // (192, 4) — 8-phase highway

  k_convm<kBED, false><<<g1, 256, 0, stream>>>(xb0, cw0, c0b, nullptr, cum, xb1);
  k_hw8<<<gh, 512, 0, stream>>>(xb1, hw0, h0b, cum, xb0);
  k_hw8<<<gh, 512, 0, stream>>>(xb0, hw0 + 1024 * kWED, h0b + 1024, cum, xb1);
  k_convm<kWED, true><<<g1, 256, 0, stream>>>(xb1, cw1, c1b, xb1, cum, xb0);
  k_hw8<<<gh, 512, 0, stream>>>(xb0, hw1, h1b, cum, xb1);
  k_hw8<<<gh, 512, 0, stream>>>(xb1, hw1 + 1024 * kWED, h1b + 1024, cum, xb0);

  k_pool<<<kMP, 128, 0, stream>>>(xb0, cum, xb1);

  dim3 g2(kMP / 128, kWED / 128);  // (128, 4)
  k_proj<<<g2, 256, 0, stream>>>(xb1, pwb, pb, (float*)d_out);
}